// Round 16
// baseline (1104.751 us; speedup 1.0000x reference)
//
#include <hip/hip_runtime.h>
#include <hip/hip_fp16.h>

#define F_IN 61
#define H 32
#define BUCK_BITS 8                  // 256 nodes per bucket
#define BUCK_SZ   256
#define CHUNK     8192               // edges per block in hist/bin passes

// ---------- scan level 1 ----------
__global__ __launch_bounds__(256) void scan1_kernel(const int* __restrict__ in,
                                                    int* __restrict__ scanned,
                                                    int* __restrict__ btot, int n) {
    __shared__ int s[256];
    int tid = threadIdx.x;
    int i = blockIdx.x * 256 + tid;
    int v = (i < n) ? in[i] : 0;
    s[tid] = v;
    __syncthreads();
    for (int off = 1; off < 256; off <<= 1) {
        int t = (tid >= off) ? s[tid - off] : 0;
        __syncthreads();
        s[tid] += t;
        __syncthreads();
    }
    if (i < n) scanned[i] = s[tid] - v;
    if (tid == 255) btot[blockIdx.x] = s[255];
}

// ---------- scan level 2 ----------
__global__ __launch_bounds__(1024) void scan2_kernel(int* __restrict__ btot, int nB) {
    __shared__ int s[1024];
    int tid = threadIdx.x;
    int v = (tid < nB) ? btot[tid] : 0;
    s[tid] = v;
    __syncthreads();
    for (int off = 1; off < 1024; off <<= 1) {
        int t = (tid >= off) ? s[tid - off] : 0;
        __syncthreads();
        s[tid] += t;
        __syncthreads();
    }
    if (tid < nB) btot[tid] = s[tid] - v;
}

// ---------- pass A: per-(block,bucket) histogram; block 0 zeroes gs + amax ----------
__global__ __launch_bounds__(256) void histA_kernel(const int* __restrict__ ei,
                                                    int* __restrict__ counts,
                                                    float* __restrict__ gs,
                                                    unsigned int* __restrict__ amax,
                                                    int E, int B, int nbuck) {
    __shared__ int h[640];
    int tid = threadIdx.x;
    if (blockIdx.x == 0) {
        #pragma unroll
        for (int r = 0; r < 8; r++) gs[r * 256 + tid] = 0.f;   // 64*H floats
        if (tid < 4) amax[tid] = 0u;
    }
    for (int i = tid; i < nbuck; i += 256) h[i] = 0;
    __syncthreads();
    int e0 = blockIdx.x * CHUNK;
    int e1 = e0 + CHUNK; if (e1 > E) e1 = E;
    for (int e = e0 + tid; e < e1; e += 256)
        atomicAdd(&h[ei[E + e] >> BUCK_BITS], 1);
    __syncthreads();
    for (int i = tid; i < nbuck; i += 256) counts[i * B + blockIdx.x] = h[i];
}

// ---------- pass B: bin edges into per-(block,bucket) EXCLUSIVE ranges ----------
__global__ __launch_bounds__(256) void binB_kernel(const int* __restrict__ ei,
                                                   const int* __restrict__ countsS,
                                                   const int* __restrict__ btot,
                                                   int* __restrict__ tmp,
                                                   int E, int B, int nbuck) {
    __shared__ int lcur[640];
    int tid = threadIdx.x;
    for (int i = tid; i < nbuck; i += 256) {
        int ci = i * B + blockIdx.x;
        lcur[i] = countsS[ci] + btot[ci >> 8];
    }
    __syncthreads();
    int e0 = blockIdx.x * CHUNK;
    int e1 = e0 + CHUNK; if (e1 > E) e1 = E;
    for (int e = e0 + tid; e < e1; e += 256) {
        int s = ei[e];
        int d = ei[E + e];
        int pos = atomicAdd(&lcur[d >> BUCK_BITS], 1);
        tmp[pos] = (s << BUCK_BITS) | (d & (BUCK_SZ - 1));
    }
}

// ---------- pass C: degrees + row_start + dinv + final CSR scatter ----------
// src_sorted stores BYTE offsets (src*32) for the u8 row tables.
// Block 0 writes the pad rows (index N, bytes=128 -> decode 0) of both tables.
__global__ __launch_bounds__(256) void binC_kernel(const int* __restrict__ countsS,
                                                   const int* __restrict__ btot,
                                                   const int* __restrict__ tmp,
                                                   int* __restrict__ src_sorted,
                                                   int* __restrict__ row_start,
                                                   float* __restrict__ dinv,
                                                   unsigned char* __restrict__ qA,
                                                   unsigned char* __restrict__ qB,
                                                   int N, int E, int B, int nbuck) {
    __shared__ int hist[BUCK_SZ];
    __shared__ int pre[BUCK_SZ];
    __shared__ int lcur[BUCK_SZ];
    int tid = threadIdx.x;
    int b = blockIdx.x;
    int base = b << BUCK_BITS;
    if (b == 0 && tid < H) {
        qA[(size_t)N * H + tid] = 128;
        qB[(size_t)N * H + tid] = 128;
    }
    int c0 = b * B;
    int e0 = countsS[c0] + btot[c0 >> 8];
    int e1 = E;
    if (b + 1 < nbuck) {
        int c1 = (b + 1) * B;
        e1 = countsS[c1] + btot[c1 >> 8];
    }
    hist[tid] = 0;
    __syncthreads();
    for (int e = e0 + tid; e < e1; e += 256)
        atomicAdd(&hist[tmp[e] & (BUCK_SZ - 1)], 1);
    __syncthreads();
    int v = hist[tid];
    pre[tid] = v;
    __syncthreads();
    for (int off = 1; off < 256; off <<= 1) {
        int t = (tid >= off) ? pre[tid - off] : 0;
        __syncthreads();
        pre[tid] += t;
        __syncthreads();
    }
    int excl = pre[tid] - v;
    int node = base + tid;
    if (node < N) {
        row_start[node] = e0 + excl;
        dinv[node] = rsqrtf((float)v + 1.0f);     // +1 self-loop
        if (node == N - 1) row_start[N] = E;
    }
    lcur[tid] = e0 + excl;
    __syncthreads();
    for (int e = e0 + tid; e < e1; e += 256) {
        int p = tmp[e];
        int pos = atomicAdd(&lcur[p & (BUCK_SZ - 1)], 1);
        src_sorted[pos] = (p >> BUCK_BITS) << 5;   // byte offset of u8 row
    }
}

// ---------- block absmax reduce -> device atomicMax (positive floats) ----------
__device__ __forceinline__ void block_amax(float a, float* red,
                                           unsigned int* __restrict__ amax) {
    int tid = threadIdx.x;
    red[tid] = a;
    __syncthreads();
    for (int off = 128; off >= 1; off >>= 1) {
        if (tid < off) red[tid] = fmaxf(red[tid], red[tid + off]);
        __syncthreads();
    }
    if (tid == 0) atomicMax(amax, __float_as_uint(red[0]));
}

// ---------- layer 1 dense: FA = fp16( dinv * (x @ W1) ), track absmax ----------
__global__ __launch_bounds__(256) void gemm1_kernel(const float* __restrict__ x,
                                                    const float* __restrict__ W,
                                                    const float* __restrict__ dinv,
                                                    __half* __restrict__ F,
                                                    unsigned int* __restrict__ amax, int N) {
    __shared__ float Ws[F_IN * H];
    __shared__ float xs[8 * F_IN];
    __shared__ float red[256];
    int tid = threadIdx.x;
    for (int i = tid; i < F_IN * H; i += 256) Ws[i] = W[i];
    int nb = blockIdx.x * 8;
    int navail = N - nb; if (navail > 8) navail = 8;
    const float* xb = x + (long long)nb * F_IN;
    for (int i = tid; i < navail * F_IN; i += 256) xs[i] = xb[i];
    __syncthreads();
    int nl = tid >> 5, f = tid & 31;
    int node = nb + nl;
    float val = 0.f;
    if (node < N) {
        float s = 0.f;
        #pragma unroll
        for (int k = 0; k < F_IN; k++) s += xs[nl * F_IN + k] * Ws[k * H + f];
        val = s * dinv[node];
        F[(long long)node * H + f] = __float2half(val);
    }
    __syncthreads();
    block_amax(fabsf(val), red, amax);
}

// ---------- requantize: fp16 staging -> u8 table with global scale ----------
// 4 features per thread: read uint2 (4 fp16), write uint (4 u8).
__global__ __launch_bounds__(256) void quant_kernel(const __half* __restrict__ F,
                                                    const unsigned int* __restrict__ amax,
                                                    unsigned char* __restrict__ q, int n4) {
    int i = blockIdx.x * 256 + threadIdx.x;
    if (i >= n4) return;
    float A = __uint_as_float(*amax);
    float inv = (A > 0.f) ? 127.f / A : 0.f;
    uint2 gv = ((const uint2*)F)[i];
    float2 f0 = __half22float2(*(__half2*)&gv.x);
    float2 f1 = __half22float2(*(__half2*)&gv.y);
    int q0 = (int)rintf(f0.x * inv) + 128;
    int q1 = (int)rintf(f0.y * inv) + 128;
    int q2 = (int)rintf(f1.x * inv) + 128;
    int q3 = (int)rintf(f1.y * inv) + 128;
    ((unsigned int*)q)[i] = (unsigned)q0 | ((unsigned)q1 << 8) |
                            ((unsigned)q2 << 16) | ((unsigned)q3 << 24);
}

// ---------- fused agg + GEMM over u8 table, GLOBAL scale ----------
// Lane map per node (32 lanes): p = lane>>4 (edge parity), fp = lane&15.
// Each lane gathers a ushort (2 u8 features) per edge; accumulates PACKED
// u16 integer sums (v_perm + add). Scale applied ONCE per node:
// sum = S*(U - 128*slots). Self-loop from fp16 staging Fin.
__global__ __launch_bounds__(256) void agg_gemm_kernel(const int* __restrict__ row_start,
                                                       const int* __restrict__ src_sorted,
                                                       const float* __restrict__ dinv,
                                                       const unsigned char* __restrict__ q,
                                                       const __half* __restrict__ Fin,
                                                       const unsigned int* __restrict__ amax_in,
                                                       const float* __restrict__ b,
                                                       const float* __restrict__ Wn,
                                                       __half* __restrict__ Fout,
                                                       unsigned int* __restrict__ amax_out,
                                                       int N) {
    __shared__ float Ws[H * H];
    __shared__ float t[8 * H];
    __shared__ float red[256];
    int tid = threadIdx.x;
    for (int i = tid; i < H * H; i += 256) Ws[i] = Wn[i];
    int nl = tid >> 5;
    int lane32 = tid & 31;
    int p = lane32 >> 4;
    int fp = lane32 & 15;
    int node = blockIdx.x * 8 + nl;
    int zoff = N << 5;
    float S = __uint_as_float(*amax_in) * (1.f / 127.f);
    unsigned acc = 0;           // packed u16x2: features 2fp (lo), 2fp+1 (hi)
    int iters = 0;              // j-iterations: 16 slots each (8 per parity)
    if (node < N) {
        const char* qbase = (const char*)q + (fp << 1);
        int e0 = row_start[node], e1 = row_start[node + 1];
        int idxv = (e0 + lane32 < e1) ? src_sorted[e0 + lane32] : zoff;
        for (int base = e0; base < e1; base += 32) {
            int w = e1 - base; if (w > 32) w = 32;
            int idxN = (base + 32 + lane32 < e1) ? src_sorted[base + 32 + lane32] : zoff;
            for (int j = 0; j < w; j += 16) {
                int offs[8];
                #pragma unroll
                for (int k = 0; k < 8; k++) offs[k] = __shfl(idxv, j + 2 * k + p, 32);
                unsigned g[8];
                #pragma unroll
                for (int k = 0; k < 8; k++)
                    g[k] = (unsigned)*(const unsigned short*)(qbase + offs[k]);
                #pragma unroll
                for (int k = 0; k < 8; k++)
                    acc += __builtin_amdgcn_perm(g[k], g[k], 0x0C010C00);
                iters++;
            }
            idxv = idxN;
        }
    }
    acc += __shfl_xor((int)acc, 16, 32);           // combine parities
    iters += __shfl_xor(iters, 16, 32);
    float val0 = 0.f, val1 = 0.f;                  // for absmax via epilogue
    if (node < N && p == 0) {
        float di = dinv[node];
        unsigned sv = *(const unsigned*)((const char*)Fin +
                          ((long long)node << 6) + (fp << 2));
        float2 s2 = __half22float2(*(__half2*)&sv);
        float2 bv = ((const float2*)b)[fp];
        float bias = 128.f * 8.f * (float)iters;   // 8 slots per parity per iter... 
        // iters already summed over both parities: slots_total = 8*iters
        float sumx = ((float)(acc & 0xFFFF) - bias) * S + s2.x;
        float sumy = ((float)(acc >> 16)    - bias) * S + s2.y;
        float rx = fmaxf(di * sumx + bv.x, 0.f);
        float ry = fmaxf(di * sumy + bv.y, 0.f);
        ((float2*)&t[nl * H])[fp] = make_float2(rx, ry);
    }
    __syncthreads();
    if (node < N) {
        int f = lane32;
        float s = 0.f;
        #pragma unroll
        for (int k = 0; k < H; k++) s += t[nl * H + k] * Ws[k * H + f];
        float v = s * dinv[node];
        Fout[(long long)node * H + f] = __float2half(v);
        val0 = fabsf(v);
    }
    __syncthreads();
    block_amax(val0 + val1 * 0.f, red, amax_out);
}

// ---------- final layer: u8 agg + relu, pool into 64 spread copies ----------
__global__ __launch_bounds__(256) void agg_pool_kernel(const int* __restrict__ row_start,
                                                       const int* __restrict__ src_sorted,
                                                       const float* __restrict__ dinv,
                                                       const unsigned char* __restrict__ q,
                                                       const __half* __restrict__ Fin,
                                                       const unsigned int* __restrict__ amax_in,
                                                       const float* __restrict__ b,
                                                       float* __restrict__ gs, int N) {
    __shared__ float t[8 * H];
    int tid = threadIdx.x;
    int nl = tid >> 5;
    int lane32 = tid & 31;
    int p = lane32 >> 4;
    int fp = lane32 & 15;
    int node = blockIdx.x * 8 + nl;
    int zoff = N << 5;
    float S = __uint_as_float(*amax_in) * (1.f / 127.f);
    unsigned acc = 0;
    int iters = 0;
    if (node < N) {
        const char* qbase = (const char*)q + (fp << 1);
        int e0 = row_start[node], e1 = row_start[node + 1];
        int idxv = (e0 + lane32 < e1) ? src_sorted[e0 + lane32] : zoff;
        for (int base = e0; base < e1; base += 32) {
            int w = e1 - base; if (w > 32) w = 32;
            int idxN = (base + 32 + lane32 < e1) ? src_sorted[base + 32 + lane32] : zoff;
            for (int j = 0; j < w; j += 16) {
                int offs[8];
                #pragma unroll
                for (int k = 0; k < 8; k++) offs[k] = __shfl(idxv, j + 2 * k + p, 32);
                unsigned g[8];
                #pragma unroll
                for (int k = 0; k < 8; k++)
                    g[k] = (unsigned)*(const unsigned short*)(qbase + offs[k]);
                #pragma unroll
                for (int k = 0; k < 8; k++)
                    acc += __builtin_amdgcn_perm(g[k], g[k], 0x0C010C00);
                iters++;
            }
            idxv = idxN;
        }
    }
    acc += __shfl_xor((int)acc, 16, 32);
    iters += __shfl_xor(iters, 16, 32);
    if (p == 0) {
        float2 r = make_float2(0.f, 0.f);
        if (node < N) {
            float di = dinv[node];
            unsigned sv = *(const unsigned*)((const char*)Fin +
                              ((long long)node << 6) + (fp << 2));
            float2 s2 = __half22float2(*(__half2*)&sv);
            float2 bv = ((const float2*)b)[fp];
            float bias = 128.f * 8.f * (float)iters;
            float sumx = ((float)(acc & 0xFFFF) - bias) * S + s2.x;
            float sumy = ((float)(acc >> 16)    - bias) * S + s2.y;
            r.x = fmaxf(di * sumx + bv.x, 0.f);
            r.y = fmaxf(di * sumy + bv.y, 0.f);
        }
        ((float2*)&t[nl * H])[fp] = r;
    }
    __syncthreads();
    if (tid < H) {
        float s = 0.f;
        #pragma unroll
        for (int rI = 0; rI < 8; rI++) s += t[rI * H + tid];
        atomicAdd(&gs[(blockIdx.x & 63) * H + tid], s);
    }
}

// ---------- head ----------
__global__ __launch_bounds__(64) void head_kernel(const float* __restrict__ gs,
                                                  const float* __restrict__ Wl1,
                                                  const float* __restrict__ bl1,
                                                  const float* __restrict__ Wl2,
                                                  const float* __restrict__ bl2,
                                                  float* __restrict__ out) {
    __shared__ float gg[H];
    __shared__ float t[16];
    int tid = threadIdx.x;
    if (tid < H) {
        float s = 0.f;
        for (int c = 0; c < 64; c++) s += gs[c * H + tid];
        gg[tid] = s;
    }
    __syncthreads();
    if (tid < 16) {
        float s = bl1[tid];
        #pragma unroll
        for (int k = 0; k < 32; k++) s += gg[k] * Wl1[k * 16 + tid];
        t[tid] = fmaxf(s, 0.f);
    }
    __syncthreads();
    if (tid < 3) {
        float s = bl2[tid];
        #pragma unroll
        for (int k = 0; k < 16; k++) s += t[k] * Wl2[k * 3 + tid];
        out[tid] = s;
    }
}

extern "C" void kernel_launch(void* const* d_in, const int* in_sizes, int n_in,
                              void* d_out, int out_size, void* d_ws, size_t ws_size,
                              hipStream_t stream) {
    const float* x   = (const float*)d_in[0];
    const int*   ei  = (const int*)d_in[1];
    const float* W1  = (const float*)d_in[2];
    const float* b1  = (const float*)d_in[3];
    const float* W2  = (const float*)d_in[4];
    const float* b2  = (const float*)d_in[5];
    const float* W3  = (const float*)d_in[6];
    const float* b3  = (const float*)d_in[7];
    const float* W4  = (const float*)d_in[8];
    const float* b4  = (const float*)d_in[9];
    const float* Wl1 = (const float*)d_in[10];
    const float* bl1 = (const float*)d_in[11];
    const float* Wl2 = (const float*)d_in[12];
    const float* bl2 = (const float*)d_in[13];
    float* out = (float*)d_out;

    const int N = in_sizes[0] / F_IN;
    const int E = in_sizes[1] / 2;
    const int nbuck = (N + BUCK_SZ - 1) >> BUCK_BITS;      // 586 for N=150000
    const int B = (E + CHUNK - 1) / CHUNK;                 // 293 for E=2.4M
    const int nC = nbuck * B;

    char* ws = (char*)d_ws;
    size_t off = 0;
    auto alloc = [&](size_t bytes) {
        char* p = ws + off;
        off += (bytes + 255) & ~(size_t)255;
        return p;
    };
    float* dinv       = (float*)alloc((size_t)N * 4);
    int*   row_start  = (int*)alloc((size_t)(N + 1) * 4);
    int*   counts     = (int*)alloc((size_t)nC * 4);
    int*   countsS    = (int*)alloc((size_t)nC * 4);
    int*   btot2      = (int*)alloc(((size_t)nC / 256 + 2) * 4);
    int*   src_sorted = (int*)alloc((size_t)E * 4);
    int*   tmp        = (int*)alloc((size_t)E * 4);
    __half* FA        = (__half*)alloc((size_t)N * H * 2);
    __half* FB        = (__half*)alloc((size_t)N * H * 2);
    unsigned char* qA = (unsigned char*)alloc((size_t)(N + 1) * H);
    unsigned char* qB = (unsigned char*)alloc((size_t)(N + 1) * H);
    unsigned int* amax = (unsigned int*)alloc(4 * 4);
    float* gs         = (float*)alloc(64 * H * 4);

    const int TB = 256;
    const int gC  = (nC + TB - 1) / TB;
    const int gN8 = (N + 7) / 8;
    const int n4  = N * H / 4;
    const int gQ  = (n4 + TB - 1) / TB;

    // ---- CSR build ----
    histA_kernel<<<B, TB, 0, stream>>>(ei, counts, gs, amax, E, B, nbuck);
    scan1_kernel<<<gC, TB, 0, stream>>>(counts, countsS, btot2, nC);
    scan2_kernel<<<1, 1024, 0, stream>>>(btot2, gC);
    binB_kernel<<<B, TB, 0, stream>>>(ei, countsS, btot2, tmp, E, B, nbuck);
    binC_kernel<<<nbuck, TB, 0, stream>>>(countsS, btot2, tmp, src_sorted, row_start,
                                          dinv, qA, qB, N, E, B, nbuck);

    // ---- layers: fp16 staging + u8 gather tables with per-layer global scale ----
    gemm1_kernel<<<gN8, TB, 0, stream>>>(x, W1, dinv, FA, &amax[0], N);
    quant_kernel<<<gQ, TB, 0, stream>>>(FA, &amax[0], qA, n4);
    agg_gemm_kernel<<<gN8, TB, 0, stream>>>(row_start, src_sorted, dinv, qA, FA,
                                            &amax[0], b1, W2, FB, &amax[1], N);
    quant_kernel<<<gQ, TB, 0, stream>>>(FB, &amax[1], qB, n4);
    agg_gemm_kernel<<<gN8, TB, 0, stream>>>(row_start, src_sorted, dinv, qB, FB,
                                            &amax[1], b2, W3, FA, &amax[2], N);
    quant_kernel<<<gQ, TB, 0, stream>>>(FA, &amax[2], qA, n4);
    agg_gemm_kernel<<<gN8, TB, 0, stream>>>(row_start, src_sorted, dinv, qA, FA,
                                            &amax[2], b3, W4, FB, &amax[3], N);
    quant_kernel<<<gQ, TB, 0, stream>>>(FB, &amax[3], qB, n4);
    agg_pool_kernel<<<gN8, TB, 0, stream>>>(row_start, src_sorted, dinv, qB, FB,
                                            &amax[3], b4, gs, N);

    head_kernel<<<1, 64, 0, stream>>>(gs, Wl1, bl1, Wl2, bl2, out);
}